// Round 1
// 9993.391 us; speedup vs baseline: 1.0723x; 1.0723x over previous
//
#include <hip/hip_runtime.h>

// ============================================================================
// R9: latency-fabric attack on the R8 structure (dependency graph unchanged).
//  - per-WG single-writer flag slots (plain agent stores, value = t, init -1);
//    lane-parallel >= polling. Kills the 25-RMW/line serialization per step.
//  - single-exposure staging: all segment loads issued up front; 2nd segment
//    latency hides under 1st segment's MFMAs. L1 phase B = one LLC round trip.
//  - ATT reduce+exp fused (one fewer sync stage).
//  - OUT staging chunks compile-time sized (no runtime-indexed reg arrays).
// Label: "R9 slot-flags + single-exposure staging"
// ============================================================================

#define DI __device__ __forceinline__

typedef _Float16 f16;
typedef _Float16 f16x8 __attribute__((ext_vector_type(8)));
typedef _Float16 f16x4 __attribute__((ext_vector_type(4)));
typedef float f32x4 __attribute__((ext_vector_type(4)));
typedef unsigned long long u64;

constexpr int Tn = 800, Un = 96, Hn = 400;
constexpr int P1 = 520, P2 = 904, P3 = 904, PM = 1288;
constexpr int NWG = 99;
constexpr int SP = 272;  // LDS staging pitch (f16)

constexpr size_t OFF_W1 = 0;
constexpr size_t SZ_W1 = (size_t)1600 * P1 * 2;
constexpr size_t OFF_W2 = OFF_W1 + SZ_W1;
constexpr size_t SZ_W2 = (size_t)1600 * P2 * 2;
constexpr size_t OFF_W3 = OFF_W2 + SZ_W2;
constexpr size_t OFF_WM = OFF_W3 + SZ_W2;
constexpr size_t SZ_WM = (size_t)128 * PM * 2;
constexpr size_t OFF_A1 = OFF_WM + SZ_WM;
constexpr size_t SZ_A1 = (size_t)2 * 64 * P1 * 2;
constexpr size_t OFF_A2 = OFF_A1 + SZ_A1;
constexpr size_t SZ_A2 = (size_t)2 * 64 * P2 * 2;
constexpr size_t OFF_A3 = OFF_A2 + SZ_A2;
constexpr size_t OFF_AM = OFF_A3 + SZ_A2;
constexpr size_t SZ_AM = (size_t)4 * 64 * PM * 2;   // quad-buffered (OUT lag)
constexpr size_t OFF_TEB = OFF_AM + SZ_AM;
constexpr size_t SZ_TEB = (size_t)64 * 96 * 64 * 2;
constexpr size_t OFF_BS1 = OFF_TEB + SZ_TEB;
constexpr size_t OFF_BS2 = OFF_BS1 + 6400;
constexpr size_t OFF_BS3 = OFF_BS2 + 6400;
constexpr size_t OFF_BW = OFF_BS3 + 6400;
constexpr size_t OFF_BM = OFF_BW + 128;
constexpr size_t OFF_FLG = OFF_BM + 512;
constexpr size_t SZ_FLG = (size_t)808 * 5 * 16 * 4;  // region kept; 160 ints used
constexpr size_t OFF_RES = OFF_FLG + SZ_FLG;

constexpr size_t O_EOS = 0, O_PI = 51200, O_MUX = 1075200, O_MUY = 2099200;
constexpr size_t O_SX = 3123200, O_SY = 4147200, O_RHO = 5171200;

// slot bases: one int per (role, wg); 32-slot (128B = 2 lines) spacing per role
constexpr int SB_L1 = 0;     // 25 slots
constexpr int SB_ATT = 32;   // 16 slots
constexpr int SB_L2 = 64;    // 25 slots
constexpr int SB_L3 = 96;    // 25 slots
constexpr int SB_OUT = 128;  // 8 slots
constexpr int NSLOT = 160;

// ---- sc1 LLC data movers ----
DI u64 ldU8(const f16* p) {
  return __hip_atomic_load((const u64*)p, __ATOMIC_RELAXED, __HIP_MEMORY_SCOPE_AGENT);
}
DI void stU8(f16* p, u64 u) {
  __hip_atomic_store((u64*)p, u, __ATOMIC_RELAXED, __HIP_MEMORY_SCOPE_AGENT);
}
DI void stA4(f16* p, f16x4 v) {
  union { f16x4 v; u64 u; } c; c.v = v;
  stU8(p, c.u);
}

// ---- slot wait: up to 4 ranges of (base, count, t_required). Lane l polls
// concatenated-list entry l and (if total>64) entry l+64. Value-based (>=),
// single writer per slot, monotone -> no ABA, no RMW. ----
DI void waitR(int* sl, int* doom,
              int b0, int n0, int q0, int b1, int n1, int q1,
              int b2, int n2, int q2, int b3, int n3, int q3) {
  if (!*doom) {
    if (threadIdx.x < 64) {
      const int l = (int)threadIdx.x;
      int sA = -1, qA = 0, sB = -1, qB = 0;
      {
        int idx = l;
        if (idx < n0) { sA = b0 + idx; qA = q0; }
        else {
          idx -= n0;
          if (idx < n1) { sA = b1 + idx; qA = q1; }
          else {
            idx -= n1;
            if (idx < n2) { sA = b2 + idx; qA = q2; }
            else {
              idx -= n2;
              if (idx < n3) { sA = b3 + idx; qA = q3; }
            }
          }
        }
      }
      {
        int idx = l + 64;
        if (idx < n0) { sB = b0 + idx; qB = q0; }
        else {
          idx -= n0;
          if (idx < n1) { sB = b1 + idx; qB = q1; }
          else {
            idx -= n1;
            if (idx < n2) { sB = b2 + idx; qB = q2; }
            else {
              idx -= n2;
              if (idx < n3) { sB = b3 + idx; qB = q3; }
            }
          }
        }
      }
      int okA = (sA < 0) ? 1 : 0, okB = (sB < 0) ? 1 : 0;
      int guard = 0;
      for (;;) {
        if (!okA)
          okA = (__hip_atomic_load(sl + sA, __ATOMIC_RELAXED, __HIP_MEMORY_SCOPE_AGENT) >= qA) ? 1 : 0;
        if (!okB)
          okB = (__hip_atomic_load(sl + sB, __ATOMIC_RELAXED, __HIP_MEMORY_SCOPE_AGENT) >= qB) ? 1 : 0;
        if (__all(okA & okB)) break;
        __builtin_amdgcn_s_sleep(1);
        if (++guard > 4000000) { if (l == 0) *doom = 1; break; }  // fail visible
      }
    }
  }
  __syncthreads();
}
// ---- arrive: syncthreads drains all waves' sc1 stores (vmcnt0) before the
// slot store, so data is globally visible before the flag value t. ----
DI void arriveS(int* sl, int slot, int t) {
  __syncthreads();
  if (threadIdx.x == 0)
    __hip_atomic_store(sl + slot, t, __ATOMIC_RELAXED, __HIP_MEMORY_SCOPE_AGENT);
}

DI float sigm(float v) { return 1.f / (1.f + expf(-v)); }

// ---- staging split into issue / write / mfma so all of a phase's LLC loads
// are issued before any is consumed (single exposed latency per phase). ----
template <int KN, int PITCH_>
DI void stage_ld(const f16* Ain, int tid, u64* lo, u64* hi) {
#pragma unroll
  for (int j = 0; j < KN; ++j) {
    const int i = tid + j * 256;
    const int r = i / (KN * 4), c16 = i % (KN * 4);
    const f16* p = Ain + (size_t)r * PITCH_ + c16 * 8;
    lo[j] = ldU8(p);
    hi[j] = ldU8(p + 4);
  }
}
template <int KN>
DI void stage_wr(f16* stg, int tid, const u64* lo, const u64* hi) {
#pragma unroll
  for (int j = 0; j < KN; ++j) {
    const int i = tid + j * 256;
    const int r = i / (KN * 4), c16 = i % (KN * 4);
    u64* q = (u64*)(stg + r * SP + c16 * 8);
    q[0] = lo[j];
    q[1] = hi[j];
  }
}
template <int KN>
DI void mfma_blk(const f16x8* wr, const f16* stg, int quad, int ln16, f32x4 acc[4]) {
#pragma unroll
  for (int ksl = 0; ksl < KN; ++ksl) {
    const int kc = ksl * 32 + quad * 8;
#pragma unroll
    for (int mt = 0; mt < 4; ++mt) {
      const f16x8 a = *(const f16x8*)(stg + (mt * 16 + ln16) * SP + kc);
      acc[mt] = __builtin_amdgcn_mfma_f32_16x16x32_f16(a, wr[ksl], acc[mt], 0, 0, 0);
    }
  }
}

// ---- gate finish: cross-wave reduce + LSTM nonlinearity + h stores ----
DI void gate_finish(f32x4 acc[4], float* red, float* cst, const float* bL, int tid,
                    int quad, int ln16, int wave,
                    f16* dA, int pA, f16* dB, int pB, f16* dC, int pC) {
#pragma unroll
  for (int mt = 0; mt < 4; ++mt)
#pragma unroll
    for (int r = 0; r < 4; ++r)
      red[wave * 1024 + (mt * 16 + quad * 4 + r) * 16 + ln16] = acc[mt][r];
  __syncthreads();
  {
    const int oi = tid * 4, b = oi >> 4, j0 = oi & 15;
    f32x4 gi = *(f32x4*)&red[oi];
    f32x4 gf = *(f32x4*)&red[1024 + oi];
    f32x4 gg = *(f32x4*)&red[2048 + oi];
    f32x4 go = *(f32x4*)&red[3072 + oi];
    f32x4 c = *(f32x4*)&cst[oi];
    f16x4 hv;
#pragma unroll
    for (int e = 0; e < 4; ++e) {
      const float iv = sigm(gi[e] + bL[j0 + e]);
      const float fv = sigm(gf[e] + bL[16 + j0 + e]);
      const float gv = tanhf(gg[e] + bL[32 + j0 + e]);
      const float ov = sigm(go[e] + bL[48 + j0 + e]);
      const float cn = fv * c[e] + iv * gv;
      c[e] = cn;
      hv[e] = (f16)(ov * tanhf(cn));
    }
    *(f32x4*)&cst[oi] = c;
    stA4(dA + b * pA + j0, hv);
    stA4(dB + b * pB + j0, hv);
    if (dC != nullptr) stA4(dC + b * pC + j0, hv);
  }
}

// ---- L1 role (25 WGs) ----
DI void l1_role(char* ws, char* smem, int jb, const float* x) {
  const int tid = threadIdx.x;
  const int wave = tid >> 6, lane = tid & 63, ln16 = lane & 15, quad = lane >> 4;
  const f16* W1 = (const f16*)(ws + OFF_W1);
  f16* A1 = (f16*)(ws + OFF_A1);
  f16* A2 = (f16*)(ws + OFF_A2);
  f16* A3 = (f16*)(ws + OFF_A3);
  f16* AM = (f16*)(ws + OFF_AM);
  int* sl = (int*)(ws + OFF_FLG);
  f16* stg = (f16*)smem;                    // 34816
  float* red = (float*)(smem + 34816);      // 16384
  float* cst = (float*)(smem + 51200);      // 4096
  float* bL = (float*)(smem + 55296);       // 256
  int* doom = (int*)(smem + 59384);
  const int row = wave * Hn + jb * 16 + ln16;
  f16x8 wr[16];
#pragma unroll
  for (int i = 0; i < 16; ++i) wr[i] = *(const f16x8*)(W1 + (size_t)row * P1 + i * 32 + quad * 8);
  if (tid < 64) bL[tid] = ((const float*)(ws + OFF_BS1))[(tid >> 4) * Hn + jb * 16 + (tid & 15)];
  for (int z = tid; z < 1024; z += 256) cst[z] = 0.f;
  if (tid == 0) *doom = 0;
  __syncthreads();
  for (int t = 0; t < Tn; ++t) {
    const f16* Ap = A1 + (size_t)(t & 1) * 64 * P1;
    f32x4 acc[4];
#pragma unroll
    for (int mt = 0; mt < 4; ++mt) acc[mt] = f32x4{0.f, 0.f, 0.f, 0.f};
    // phase A: h1 rec ks2..13 (needs only own role t-1); one exposed latency
    waitR(sl, doom, SB_L1, 25, t - 1, 0, 0, 0, 0, 0, 0, 0, 0, 0);
    {
      u64 lo8[8], hi8[8], lo4[4], hi4[4];
      stage_ld<8, P1>(Ap + 2 * 32, tid, lo8, hi8);
      stage_wr<8>(stg, tid, lo8, hi8);     // stg free (waitR's barrier)
      stage_ld<4, P1>(Ap + 10 * 32, tid, lo4, hi4);  // hides under mfma<8>
      __syncthreads();
      mfma_blk<8>(wr + 2, stg, quad, ln16, acc);
      __syncthreads();
      stage_wr<4>(stg, tid, lo4, hi4);
      __syncthreads();
      mfma_blk<4>(wr + 10, stg, quad, ln16, acc);
    }
    // phase B: w + x (ks0,1,14) after ATT(t-1); WAR flags for our writes
    waitR(sl, doom, SB_ATT, 16, t - 1, SB_L2, 25, t - 2, SB_L3, 25, t - 2, SB_OUT, 8, t - 4);
    if (jb == 0 && tid < 64) {  // broadcast x(t) into A2/A3 current slot
      const float* xp = x + ((size_t)tid * Tn + t) * 3;
      f16x4 xv = {(f16)xp[0], (f16)xp[1], (f16)xp[2], (f16)0.f};
      stA4(A2 + (size_t)(t & 1) * 64 * P2 + tid * P2 + 464, xv);
      stA4(A3 + (size_t)(t & 1) * 64 * P3 + tid * P3 + 464, xv);
    }
    {
      u64 lo2[2], hi2[2], lo1[1], hi1[1];
      stage_ld<2, P1>(Ap + 0, tid, lo2, hi2);
      stage_ld<1, P1>(Ap + 14 * 32, tid, lo1, hi1);
      stage_wr<2>(stg, tid, lo2, hi2);          // cols 0..63
      stage_wr<1>(stg + 64, tid, lo1, hi1);     // cols 64..95
      __syncthreads();
      mfma_blk<2>(wr + 0, stg, quad, ln16, acc);
      mfma_blk<1>(wr + 14, stg + 64, quad, ln16, acc);
    }
    // ks15 = pure zero padding: skipped
    gate_finish(acc, red, cst, bL, tid, quad, ln16, wave,
                A1 + (size_t)((t + 1) & 1) * 64 * P1 + 64 + jb * 16, P1,
                A2 + (size_t)(t & 1) * 64 * P2 + 64 + jb * 16, P2,
                AM + (size_t)(t & 3) * 64 * PM + jb * 16, PM);
    arriveS(sl, SB_L1 + jb, t);
  }
}

// ---- L2 role (25 WGs) ----
DI void l2_role(char* ws, char* smem, int jb) {
  const int tid = threadIdx.x;
  const int wave = tid >> 6, lane = tid & 63, ln16 = lane & 15, quad = lane >> 4;
  const f16* W2 = (const f16*)(ws + OFF_W2);
  f16* A2 = (f16*)(ws + OFF_A2);
  f16* A3 = (f16*)(ws + OFF_A3);
  f16* AM = (f16*)(ws + OFF_AM);
  int* sl = (int*)(ws + OFF_FLG);
  f16* stg = (f16*)smem;
  float* red = (float*)(smem + 34816);
  float* cst = (float*)(smem + 51200);
  float* bL = (float*)(smem + 55296);
  int* doom = (int*)(smem + 59384);
  const int row = wave * Hn + jb * 16 + ln16;
  f16x8 wr[28];
#pragma unroll
  for (int i = 0; i < 28; ++i) wr[i] = *(const f16x8*)(W2 + (size_t)row * P2 + i * 32 + quad * 8);
  if (tid < 64) bL[tid] = ((const float*)(ws + OFF_BS2))[(tid >> 4) * Hn + jb * 16 + (tid & 15)];
  for (int z = tid; z < 1024; z += 256) cst[z] = 0.f;
  if (tid == 0) *doom = 0;
  __syncthreads();
  for (int t = 0; t < Tn; ++t) {
    const f16* Ap = A2 + (size_t)(t & 1) * 64 * P2;
    f32x4 acc[4];
#pragma unroll
    for (int mt = 0; mt < 4; ++mt) acc[mt] = f32x4{0.f, 0.f, 0.f, 0.f};
    // phase A: h2rec ks15..27 (own role t-1)
    waitR(sl, doom, SB_L2, 25, t - 1, 0, 0, 0, 0, 0, 0, 0, 0, 0);
    {
      u64 lo8[8], hi8[8], lo5[5], hi5[5];
      stage_ld<8, P2>(Ap + 15 * 32, tid, lo8, hi8);
      stage_wr<8>(stg, tid, lo8, hi8);
      stage_ld<5, P2>(Ap + 23 * 32, tid, lo5, hi5);
      __syncthreads();
      mfma_blk<8>(wr + 15, stg, quad, ln16, acc);
      __syncthreads();
      stage_wr<5>(stg, tid, lo5, hi5);
      __syncthreads();
      mfma_blk<5>(wr + 23, stg, quad, ln16, acc);
    }
    // phase B: h1 + x ks2..14 (needs L1(t))
    waitR(sl, doom, SB_L1, 25, t, 0, 0, 0, 0, 0, 0, 0, 0, 0);
    {
      u64 lo8[8], hi8[8], lo5[5], hi5[5];
      stage_ld<8, P2>(Ap + 2 * 32, tid, lo8, hi8);
      stage_wr<8>(stg, tid, lo8, hi8);
      stage_ld<5, P2>(Ap + 10 * 32, tid, lo5, hi5);
      __syncthreads();
      mfma_blk<8>(wr + 2, stg, quad, ln16, acc);
      __syncthreads();
      stage_wr<5>(stg, tid, lo5, hi5);
      __syncthreads();
      mfma_blk<5>(wr + 10, stg, quad, ln16, acc);
    }
    // phase C: w ks0..1 (needs ATT(t)); WAR flags for our writes
    waitR(sl, doom, SB_ATT, 16, t, SB_L3, 25, t - 2, SB_OUT, 8, t - 4, 0, 0, 0);
    {
      u64 lo2[2], hi2[2];
      stage_ld<2, P2>(Ap + 0, tid, lo2, hi2);
      stage_wr<2>(stg, tid, lo2, hi2);
      __syncthreads();
      mfma_blk<2>(wr + 0, stg, quad, ln16, acc);
    }
    gate_finish(acc, red, cst, bL, tid, quad, ln16, wave,
                A2 + (size_t)((t + 1) & 1) * 64 * P2 + 480 + jb * 16, P2,
                A3 + (size_t)(t & 1) * 64 * P3 + 64 + jb * 16, P3,
                AM + (size_t)(t & 3) * 64 * PM + Hn + jb * 16, PM);
    arriveS(sl, SB_L2 + jb, t);
  }
}

// ---- L3 role (25 WGs) ----
DI void l3_role(char* ws, char* smem, int jb) {
  const int tid = threadIdx.x;
  const int wave = tid >> 6, lane = tid & 63, ln16 = lane & 15, quad = lane >> 4;
  const f16* W3 = (const f16*)(ws + OFF_W3);
  f16* A3 = (f16*)(ws + OFF_A3);
  f16* AM = (f16*)(ws + OFF_AM);
  int* sl = (int*)(ws + OFF_FLG);
  f16* stg = (f16*)smem;
  float* red = (float*)(smem + 34816);
  float* cst = (float*)(smem + 51200);
  float* bL = (float*)(smem + 55296);
  int* doom = (int*)(smem + 59384);
  const int row = wave * Hn + jb * 16 + ln16;
  f16x8 wr[28];
#pragma unroll
  for (int i = 0; i < 28; ++i) wr[i] = *(const f16x8*)(W3 + (size_t)row * P3 + i * 32 + quad * 8);
  if (tid < 64) bL[tid] = ((const float*)(ws + OFF_BS3))[(tid >> 4) * Hn + jb * 16 + (tid & 15)];
  for (int z = tid; z < 1024; z += 256) cst[z] = 0.f;
  if (tid == 0) *doom = 0;
  __syncthreads();
  for (int t = 0; t < Tn; ++t) {
    const f16* Ap = A3 + (size_t)(t & 1) * 64 * P3;
    f32x4 acc[4];
#pragma unroll
    for (int mt = 0; mt < 4; ++mt) acc[mt] = f32x4{0.f, 0.f, 0.f, 0.f};
    // phase A: h3rec ks15..27 (own role t-1)
    waitR(sl, doom, SB_L3, 25, t - 1, 0, 0, 0, 0, 0, 0, 0, 0, 0);
    {
      u64 lo8[8], hi8[8], lo5[5], hi5[5];
      stage_ld<8, P3>(Ap + 15 * 32, tid, lo8, hi8);
      stage_wr<8>(stg, tid, lo8, hi8);
      stage_ld<5, P3>(Ap + 23 * 32, tid, lo5, hi5);
      __syncthreads();
      mfma_blk<8>(wr + 15, stg, quad, ln16, acc);
      __syncthreads();
      stage_wr<5>(stg, tid, lo5, hi5);
      __syncthreads();
      mfma_blk<5>(wr + 23, stg, quad, ln16, acc);
    }
    // phase B: h2 + x ks2..14 (needs L2(t); x under RL1(t) < RL2(t) temporally)
    waitR(sl, doom, SB_L2, 25, t, 0, 0, 0, 0, 0, 0, 0, 0, 0);
    {
      u64 lo8[8], hi8[8], lo5[5], hi5[5];
      stage_ld<8, P3>(Ap + 2 * 32, tid, lo8, hi8);
      stage_wr<8>(stg, tid, lo8, hi8);
      stage_ld<5, P3>(Ap + 10 * 32, tid, lo5, hi5);
      __syncthreads();
      mfma_blk<8>(wr + 2, stg, quad, ln16, acc);
      __syncthreads();
      stage_wr<5>(stg, tid, lo5, hi5);
      __syncthreads();
      mfma_blk<5>(wr + 10, stg, quad, ln16, acc);
    }
    // phase C: w ks0..1 (needs ATT(t)); WAR for AM write
    waitR(sl, doom, SB_ATT, 16, t, SB_OUT, 8, t - 4, 0, 0, 0, 0, 0, 0);
    {
      u64 lo2[2], hi2[2];
      stage_ld<2, P3>(Ap + 0, tid, lo2, hi2);
      stage_wr<2>(stg, tid, lo2, hi2);
      __syncthreads();
      mfma_blk<2>(wr + 0, stg, quad, ln16, acc);
    }
    gate_finish(acc, red, cst, bL, tid, quad, ln16, wave,
                A3 + (size_t)((t + 1) & 1) * 64 * P3 + 480 + jb * 16, P3,
                AM + (size_t)(t & 3) * 64 * PM + 2 * Hn + jb * 16, PM,
                nullptr, 0);
    arriveS(sl, SB_L3 + jb, t);
  }
}

// ---- attention role (16 WGs x 4 batches) ----
DI void att_role(char* ws, char* smem, int ab, const float* x, const float* Ww) {
  const int tid = threadIdx.x;
  const int b0 = ab * 4;
  f16* A1 = (f16*)(ws + OFF_A1);
  f16* A2 = (f16*)(ws + OFF_A2);
  f16* A3 = (f16*)(ws + OFF_A3);
  int* sl = (int*)(ws + OFF_FLG);
  f16* tebL = (f16*)smem;                 // 49152
  f16* h1L = (f16*)(smem + 49152);        // 3200
  float* ps = (float*)(smem + 52352);     // 3840
  float* aL = (float*)(smem + 56672);     // 160
  float* beL = (float*)(smem + 56832);    // 160
  float* kaL = (float*)(smem + 56992);    // 160 (persistent kappa)
  float* phiL = (float*)(smem + 57152);   // 1536
  float* bwL = (float*)(smem + 58688);    // 120
  f16* wL = (f16*)(smem + 58816);         // 512
  int* doom = (int*)(smem + 59384);
  const int pr = tid >> 3, psd = tid & 7;
  float wwr[50];
  if (tid < 240) {
#pragma unroll
    for (int k = 0; k < 50; ++k) wwr[k] = Ww[pr * 400 + psd * 50 + k];
  }
  for (int i = tid; i < 24576; i += 256)
    tebL[i] = ((const f16*)(ws + OFF_TEB))[(size_t)b0 * 6144 + i];
  if (tid < 40) kaL[tid] = 0.f;
  if (tid < 30) bwL[tid] = ((const float*)(ws + OFF_BW))[tid];
  if (tid == 0) *doom = 0;
  __syncthreads();

  for (int t = 0; t < Tn; ++t) {
    waitR(sl, doom, SB_L1, 25, t, SB_L2, 25, t - 2, SB_L3, 25, t - 2, 0, 0, 0);
    {
      const f16* h1p = A2 + (size_t)(t & 1) * 64 * P2;
      for (int i = tid; i < 400; i += 256) {  // 4 batches x 100 u64 of h1 (sc1)
        const int b = i / 100, c = i % 100;
        ((u64*)h1L)[i] = ldU8(h1p + (b0 + b) * P2 + 64 + c * 4);
      }
      __syncthreads();
      if (tid < 240) {
#pragma unroll 1
        for (int b = 0; b < 4; ++b) {
          const f16* hh = &h1L[b * 400 + psd * 50];
          float a = 0.f;
#pragma unroll
          for (int k = 0; k < 50; ++k) a += wwr[k] * (float)hh[k];
          ps[(b * 30 + pr) * 8 + psd] = a;
        }
      }
      __syncthreads();
      if (tid < 120) {  // fused reduce + exp (alpha/beta/kappa direct)
        const int b = tid / 30, r = tid % 30;
        float v = bwL[r];
#pragma unroll
        for (int s = 0; s < 8; ++s) v += ps[(b * 30 + r) * 8 + s];
        if (r < 10) aL[b * 10 + r] = expf(v);
        else if (r < 20) beL[b * 10 + r - 10] = expf(v);
        else kaL[b * 10 + r - 20] += expf(fminf(5.f, fmaxf(-10.f, v)));
      }
      __syncthreads();
      for (int idx = tid; idx < 384; idx += 256) {
        const int b = idx / 96;
        const float u1 = (float)(idx % 96 + 1);
        float s = 0.f;
#pragma unroll
        for (int k = 0; k < 10; ++k) {
          const float d = kaL[b * 10 + k] - u1;
          s += aL[b * 10 + k] * expf(-beL[b * 10 + k] * d * d);
        }
        phiL[idx] = s;
      }
      __syncthreads();
      {
        const int b = tid >> 6, d = tid & 63;
        float wv = 0.f;
        for (int u = 0; u < 96; ++u) wv += phiL[b * 96 + u] * (float)tebL[(b * 96 + u) * 64 + d];
        wL[tid] = (f16)wv;
      }
      __syncthreads();
      if (tid < 64) {  // w(t) -> L1(t+1), L2(t), L3(t)
        const u64 wq = ((u64*)wL)[tid];
        const int bg = b0 + (tid >> 4), d0 = (tid & 15) * 4;
        stU8(A1 + (size_t)((t + 1) & 1) * 64 * P1 + bg * P1 + d0, wq);
        stU8(A2 + (size_t)(t & 1) * 64 * P2 + bg * P2 + d0, wq);
        stU8(A3 + (size_t)(t & 1) * 64 * P3 + bg * P3 + d0, wq);
      }
      if (t + 1 < Tn && tid < 4) {  // stage x(t+1) into A1 next slot only
        const int b = b0 + tid;
        const float* xp = x + ((size_t)b * Tn + (t + 1)) * 3;
        f16x4 xv = {(f16)xp[0], (f16)xp[1], (f16)xp[2], (f16)0.f};
        stA4(A1 + (size_t)((t + 1) & 1) * 64 * P1 + b * P1 + 464, xv);
      }
    }
    arriveS(sl, SB_ATT + ab, t);
  }
}

// ---- OUT staging chunk (compile-time KN; no runtime-indexed reg arrays) ----
template <int KN>
DI void out_chunk(const f16* Ap, const f16x8* wm, f16* stg, int tid, int wave,
                  int quad, int ln16, f32x4& acc) {
  u64 lo[KN], hi[KN];
#pragma unroll
  for (int j = 0; j < KN; ++j) {
    const int i = tid + j * 256;
    const int r = i / (KN * 4), c16 = i % (KN * 4);
    const f16* p = Ap + (size_t)r * PM + c16 * 8;
    lo[j] = ldU8(p);
    hi[j] = ldU8(p + 4);
  }
  __syncthreads();
#pragma unroll
  for (int j = 0; j < KN; ++j) {
    const int i = tid + j * 256;
    const int r = i / (KN * 4), c16 = i % (KN * 4);
    u64* q = (u64*)(stg + r * SP + c16 * 8);
    q[0] = lo[j];
    q[1] = hi[j];
  }
  __syncthreads();
#pragma unroll
  for (int ksl = 0; ksl < KN; ++ksl) {
    const f16x8 a = *(const f16x8*)(stg + (wave * 16 + ln16) * SP + ksl * 32 + quad * 8);
    acc = __builtin_amdgcn_mfma_f32_16x16x32_f16(a, wm[ksl], acc, 0, 0, 0);
  }
}

// ---- output role (8 WGs): wave-per-m16, K=40 (pad ks38-39 skipped) ----
DI void out_role(char* ws, char* smem, int nt) {
  const int tid = threadIdx.x;
  const int wave = tid >> 6, lane = tid & 63, ln16 = lane & 15, quad = lane >> 4;
  const f16* WM = (const f16*)(ws + OFF_WM);
  const f16* AM = (const f16*)(ws + OFF_AM);
  float* resb = (float*)(ws + OFF_RES);
  int* sl = (int*)(ws + OFF_FLG);
  f16* stg = (f16*)smem;                  // 34816
  float* bmL = (float*)(smem + 34816);    // 64
  int* doom = (int*)(smem + 59384);
  f16x8 wm[38];
#pragma unroll
  for (int i = 0; i < 38; ++i)
    wm[i] = *(const f16x8*)(WM + (size_t)(nt * 16 + ln16) * PM + i * 32 + quad * 8);
  if (tid < 16) bmL[tid] = ((const float*)(ws + OFF_BM))[nt * 16 + tid];
  if (tid == 0) *doom = 0;
  __syncthreads();

  for (int t = 0; t < Tn; ++t) {
    waitR(sl, doom, SB_L1, 25, t, SB_L2, 25, t, SB_L3, 25, t, 0, 0, 0);
    const f16* Ap = AM + (size_t)(t & 3) * 64 * PM;
    f32x4 acc = f32x4{0.f, 0.f, 0.f, 0.f};
    out_chunk<8>(Ap + 0 * 32, wm + 0, stg, tid, wave, quad, ln16, acc);
    out_chunk<8>(Ap + 8 * 32, wm + 8, stg, tid, wave, quad, ln16, acc);
    out_chunk<8>(Ap + 16 * 32, wm + 16, stg, tid, wave, quad, ln16, acc);
    out_chunk<8>(Ap + 24 * 32, wm + 24, stg, tid, wave, quad, ln16, acc);
    out_chunk<6>(Ap + 32 * 32, wm + 32, stg, tid, wave, quad, ln16, acc);
#pragma unroll
    for (int e = 0; e < 4; ++e) {  // C-layout: col=lane&15, row=quad*4+e
      const int m = wave * 16 + quad * 4 + e;
      resb[((size_t)t * 64 + m) * 128 + nt * 16 + ln16] = acc[e] + bmL[ln16];
    }
    arriveS(sl, SB_OUT + nt, t);
  }
}

__global__ void __launch_bounds__(256, 1) coop_kernel(char* ws, const float* x, const float* Ww) {
  __shared__ char smem[59392];
  const int id = (int)blockIdx.x;
  if (id < 25) l1_role(ws, smem, id, x);
  else if (id < 50) l2_role(ws, smem, id - 25);
  else if (id < 75) l3_role(ws, smem, id - 50);
  else if (id < 91) att_role(ws, smem, id - 75, x, Ww);
  else out_role(ws, smem, id - 91);
}

// ---- init: f16 weight layouts, zero A-buffers, slots, text emb ----
__global__ void init_build(char* ws, const int* tok, const float* emb,
                           const float* Wih1, const float* Whh1, const float* bih1, const float* bhh1,
                           const float* Wih2, const float* Whh2, const float* bih2, const float* bhh2,
                           const float* Wih3, const float* Whh3, const float* bih3, const float* bhh3,
                           const float* bw, const float* Wm, const float* bm) {
  const int blk = (int)blockIdx.x, tid = (int)threadIdx.x;
  if (blk < 1600) {
    const int j = blk;
    f16* W1 = (f16*)(ws + OFF_W1) + (size_t)j * P1;
    f16* W2 = (f16*)(ws + OFF_W2) + (size_t)j * P2;
    f16* W3 = (f16*)(ws + OFF_W3) + (size_t)j * P2;
    for (int c = tid; c < P1; c += 256) {
      float v = 0.f;
      if (c < 64) v = Wih1[(size_t)j * 67 + 3 + c];
      else if (c < 464) v = Whh1[(size_t)j * 400 + c - 64];
      else if (c < 467) v = Wih1[(size_t)j * 67 + c - 464];
      W1[c] = (f16)v;
    }
    for (int c = tid; c < P2; c += 256) {
      float v2 = 0.f, v3 = 0.f;
      if (c < 64) { v2 = Wih2[(size_t)j * 467 + 403 + c]; v3 = Wih3[(size_t)j * 467 + 403 + c]; }
      else if (c < 464) { v2 = Wih2[(size_t)j * 467 + 3 + c - 64]; v3 = Wih3[(size_t)j * 467 + 3 + c - 64]; }
      else if (c < 467) { v2 = Wih2[(size_t)j * 467 + c - 464]; v3 = Wih3[(size_t)j * 467 + c - 464]; }
      else if (c >= 480 && c < 880) { v2 = Whh2[(size_t)j * 400 + c - 480]; v3 = Whh3[(size_t)j * 400 + c - 480]; }
      W2[c] = (f16)v2;
      W3[c] = (f16)v3;
    }
  } else if (blk < 1728) {
    const int r = blk - 1600;
    f16* WMp = (f16*)(ws + OFF_WM) + (size_t)r * PM;
    for (int c = tid; c < PM; c += 256) {
      const float v = (r < 121 && c < 1200) ? Wm[(size_t)r * 1200 + c] : 0.f;
      WMp[c] = (f16)v;
    }
  } else if (blk == 1728) {
    float* bs1 = (float*)(ws + OFF_BS1);
    float* bs2 = (float*)(ws + OFF_BS2);
    float* bs3 = (float*)(ws + OFF_BS3);
    for (int i = tid; i < 1600; i += 256) {
      bs1[i] = bih1[i] + bhh1[i];
      bs2[i] = bih2[i] + bhh2[i];
      bs3[i] = bih3[i] + bhh3[i];
    }
    float* bwp = (float*)(ws + OFF_BW);
    if (tid < 32) bwp[tid] = (tid < 30) ? bw[tid] : 0.f;
    float* bmp = (float*)(ws + OFF_BM);
    if (tid < 128) bmp[tid] = (tid < 121) ? bm[tid] : 0.f;
  } else if (blk == 1729) {
    int* fl = (int*)(ws + OFF_FLG);
    for (int i = tid; i < NSLOT; i += 256) fl[i] = -1;  // "t=-1 done" preset
  } else if (blk < 1762) {
    unsigned* az = (unsigned*)(ws + OFF_A1);  // A1,A2,A3,AM contiguous
    const int n = (int)((SZ_A1 + 2 * SZ_A2 + SZ_AM) / 4);
    for (int i = (blk - 1730) * 256 + tid; i < n; i += 32 * 256) az[i] = 0u;
  } else {
    f16* tebp = (f16*)(ws + OFF_TEB);
    const int n = 64 * 96 * 64;
    for (int i = (blk - 1762) * 256 + tid; i < n; i += 128 * 256) {
      const int b = i / (96 * 64);
      const int rem = i % (96 * 64);
      const int u = rem >> 6, d = rem & 63;
      const int tk = tok[b * 96 + u];
      tebp[i] = (f16)emb[(size_t)tk * 64 + d];
    }
  }
}

__global__ void init_x0(char* ws, const float* x) {
  const int tid = (int)threadIdx.x;
  if (tid < 192) {
    const int b = tid / 3, k = tid % 3;
    ((f16*)(ws + OFF_A1))[(size_t)b * P1 + 464 + k] = (f16)x[(size_t)b * Tn * 3 + k];
  }
}

// ---- epilogue: res -> (eos, softmax pi, mu, sigma, rho) ----
__global__ void postproc(const char* ws, float* out) {
  __shared__ float r[50 * 128];
  __shared__ float mx[50], dn[50];
  const float* resb = (const float*)(ws + OFF_RES);
  const int tid = (int)threadIdx.x;
  const int b = (int)blockIdx.x >> 4;
  const int t0 = ((int)blockIdx.x & 15) * 50;
  for (int idx = tid; idx < 50 * 128; idx += 256) {
    const int tt = idx >> 7, c = idx & 127;
    r[idx] = resb[((size_t)(t0 + tt) * 64 + b) * 128 + c];
  }
  __syncthreads();
  if (tid < 50) {
    float m = -1e30f;
    for (int k = 0; k < 20; ++k) m = fmaxf(m, r[tid * 128 + 1 + k]);
    float s = 0.f;
    for (int k = 0; k < 20; ++k) s += expf(r[tid * 128 + 1 + k] - m);
    mx[tid] = m;
    dn[tid] = 1.f / s;
  }
  __syncthreads();
  for (int idx = tid; idx < 50; idx += 256)
    out[O_EOS + (size_t)b * Tn + t0 + idx] = r[idx * 128];
  for (int idx = tid; idx < 50 * 20; idx += 256) {
    const int tt = idx / 20, k = idx % 20;
    const size_t o = ((size_t)b * Tn + t0 + tt) * 20 + k;
    const float* rr = &r[tt * 128];
    out[O_PI + o] = expf(rr[1 + k] - mx[tt]) * dn[tt];
    out[O_MUX + o] = rr[21 + k];
    out[O_MUY + o] = rr[41 + k];
    out[O_SX + o] = expf(rr[61 + k]) + 1e-6f;
    out[O_SY + o] = expf(rr[81 + k]) + 1e-6f;
    out[O_RHO + o] = tanhf(rr[101 + k]) * 0.999f;
  }
}

extern "C" void kernel_launch(void* const* d_in, const int* in_sizes, int n_in,
                              void* d_out, int out_size, void* d_ws, size_t ws_size,
                              hipStream_t stream) {
  const float* x = (const float*)d_in[0];
  const int* tok = (const int*)d_in[1];
  const float* emb = (const float*)d_in[2];
  const float* Wih1 = (const float*)d_in[3];
  const float* Whh1 = (const float*)d_in[4];
  const float* bih1 = (const float*)d_in[5];
  const float* bhh1 = (const float*)d_in[6];
  const float* Wih2 = (const float*)d_in[7];
  const float* Whh2 = (const float*)d_in[8];
  const float* bih2 = (const float*)d_in[9];
  const float* bhh2 = (const float*)d_in[10];
  const float* Wih3 = (const float*)d_in[11];
  const float* Whh3 = (const float*)d_in[12];
  const float* bih3 = (const float*)d_in[13];
  const float* bhh3 = (const float*)d_in[14];
  const float* Ww = (const float*)d_in[15];
  const float* bw = (const float*)d_in[16];
  const float* Wm = (const float*)d_in[17];
  const float* bm = (const float*)d_in[18];
  char* ws = (char*)d_ws;
  float* out = (float*)d_out;

  hipLaunchKernelGGL(init_build, dim3(1890), dim3(256), 0, stream,
                     ws, tok, emb, Wih1, Whh1, bih1, bhh1, Wih2, Whh2, bih2, bhh2,
                     Wih3, Whh3, bih3, bhh3, bw, Wm, bm);
  hipLaunchKernelGGL(init_x0, dim3(1), dim3(256), 0, stream, ws, x);

  hipLaunchKernelGGL(coop_kernel, dim3(NWG), dim3(256), 0, stream, ws, x, Ww);

  hipLaunchKernelGGL(postproc, dim3(1024), dim3(256), 0, stream, ws, out);
}